// Round 2
// baseline (551.290 us; speedup 1.0000x reference)
//
#include <hip/hip_runtime.h>
#include <cstdint>

#define BB 8
#define NN 16384
#define DD 128
#define KK 10
#define N_ITERS 7
#define LN_EPS 1e-5f
#define ATT_EPS 1e-8f

#define KV_R 32
#define KV_BPB (NN / KV_R)      // 512 blocks per batch
#define NCH_SZ 128
#define NCH (NN / NCH_SZ)       // 128 chunks per batch

// ---- workspace layout (floats) ----
#define OFF_KPT   ((size_t)0)
#define OFF_VP    (OFF_KPT + (size_t)BB * DD * NN)
#define OFF_Q     (OFF_VP + (size_t)BB * NN * DD)
#define OFF_SLOTS (OFF_Q + (size_t)BB * KK * DD)
#define OFF_UPART (OFF_SLOTS + (size_t)BB * KK * DD)
#define OFF_DPART (OFF_UPART + (size_t)BB * NCH * KK * DD)
#define OFF_SVP   (OFF_DPART + (size_t)BB * NCH * KK)
#define OFF_SUMV  (OFF_SVP + (size_t)BB * KV_BPB * DD)
#define OFF_WIHT  (OFF_SUMV + (size_t)BB * DD)
#define OFF_WHHT  (OFF_WIHT + (size_t)3 * DD * DD)

// ------------------------------------------------------------------
// Transpose Wih/Whh ([3D][D] -> [D][3D]) for coalesced GRU reads.
__global__ void k_transpose(const float* __restrict__ Wih, const float* __restrict__ Whh,
                            float* __restrict__ WihT, float* __restrict__ WhhT) {
    int idx = blockIdx.x * 256 + threadIdx.x;
    if (idx < 3 * DD * DD) {
        int d = idx / (3 * DD);
        int j = idx % (3 * DD);
        WihT[idx] = Wih[j * DD + d];
        WhhT[idx] = Whh[j * DD + d];
    }
}

// ------------------------------------------------------------------
// Fused LayerNorm + K/V projection. Block = 128 threads handles KV_R rows.
// Writes kpt transposed [B][D][N], vp row-major [B][N][D], and per-block
// partial column-sums of v (for the eps*sum_v term).
__global__ __launch_bounds__(128) void k_ln_kv(
        const float* __restrict__ x,
        const float* __restrict__ Wk, const float* __restrict__ bk,
        const float* __restrict__ Wv, const float* __restrict__ bv,
        const float* __restrict__ g_in, const float* __restrict__ b_in,
        float* __restrict__ kpt, float* __restrict__ vp, float* __restrict__ svp) {
    __shared__ float xt[DD][KV_R + 4];   // transposed tile, row stride 36 floats (16B aligned)
    __shared__ float s1[KV_R][4], s2[KV_R][4];
    __shared__ float mean_s[KV_R], rs_s[KV_R];

    int tid = threadIdx.x;
    int blk = blockIdx.x;
    int b   = blk / KV_BPB;
    int cb  = blk % KV_BPB;
    int n0  = cb * KV_R;

    const float* xp = x + ((size_t)b * NN + n0) * DD;
    // load: thread tid owns column e = tid across all rows
    #pragma unroll 4
    for (int r = 0; r < KV_R; r++) {
        xt[tid][r] = xp[(size_t)r * DD + tid];
    }
    __syncthreads();

    // per-row stats: 4 partial threads per row
    {
        int r = tid >> 2, p = tid & 3;
        float s = 0.f, sq = 0.f;
        #pragma unroll 8
        for (int i = 0; i < 32; i++) {
            float v = xt[p * 32 + i][r];
            s += v; sq += v * v;
        }
        s1[r][p] = s; s2[r][p] = sq;
    }
    __syncthreads();
    if (tid < KV_R) {
        float s  = s1[tid][0] + s1[tid][1] + s1[tid][2] + s1[tid][3];
        float sq = s2[tid][0] + s2[tid][1] + s2[tid][2] + s2[tid][3];
        float m  = s * (1.0f / DD);
        float var = sq * (1.0f / DD) - m * m;
        mean_s[tid] = m;
        rs_s[tid]   = rsqrtf(var + LN_EPS);
    }
    __syncthreads();
    {
        float ge = g_in[tid], be = b_in[tid];
        #pragma unroll 4
        for (int r = 0; r < KV_R; r++) {
            xt[tid][r] = (xt[tid][r] - mean_s[r]) * rs_s[r] * ge + be;
        }
    }
    __syncthreads();

    // projection: thread tid owns output column c for both K and V
    int c = tid;
    float acck[KV_R], accv[KV_R];
    #pragma unroll
    for (int r = 0; r < KV_R; r++) { acck[r] = 0.f; accv[r] = 0.f; }

    for (int e = 0; e < DD; e++) {
        float wk = Wk[e * DD + c];
        float wv = Wv[e * DD + c];
        const float4* row = (const float4*)&xt[e][0];
        #pragma unroll
        for (int g = 0; g < KV_R / 4; g++) {
            float4 v4 = row[g];
            acck[4 * g + 0] += v4.x * wk;  accv[4 * g + 0] += v4.x * wv;
            acck[4 * g + 1] += v4.y * wk;  accv[4 * g + 1] += v4.y * wv;
            acck[4 * g + 2] += v4.z * wk;  accv[4 * g + 2] += v4.z * wv;
            acck[4 * g + 3] += v4.w * wk;  accv[4 * g + 3] += v4.w * wv;
        }
    }

    float bkc = bk[c], bvc = bv[c];
    float* kdst = kpt + ((size_t)b * DD + c) * NN + n0;
    #pragma unroll
    for (int r = 0; r < KV_R; r++) kdst[r] = acck[r] + bkc;

    float sv = 0.f;
    #pragma unroll
    for (int r = 0; r < KV_R; r++) {
        float vv = accv[r] + bvc;
        vp[((size_t)b * NN + n0 + r) * DD + c] = vv;
        sv += vv;
    }
    svp[((size_t)b * KV_BPB + cb) * DD + c] = sv;
}

// ------------------------------------------------------------------
__global__ __launch_bounds__(128) void k_sumv(const float* __restrict__ svp,
                                              float* __restrict__ sumv) {
    int b = blockIdx.x, c = threadIdx.x;
    float s = 0.f;
    for (int cb = 0; cb < KV_BPB; cb++) s += svp[((size_t)b * KV_BPB + cb) * DD + c];
    sumv[b * DD + c] = s;
}

// ------------------------------------------------------------------
// block-wide LN stats over 128 threads (one value per thread)
__device__ inline void block_stats(float v, float& mean, float& rstd, float* red) {
    float s = v, sq = v * v;
    #pragma unroll
    for (int o = 32; o > 0; o >>= 1) {
        s  += __shfl_down(s, o, 64);
        sq += __shfl_down(sq, o, 64);
    }
    int lane = threadIdx.x & 63, w = threadIdx.x >> 6;
    if (lane == 0) { red[w * 2] = s; red[w * 2 + 1] = sq; }
    __syncthreads();
    float S = red[0] + red[2], SQ = red[1] + red[3];
    mean = S * (1.0f / DD);
    float var = SQ * (1.0f / DD) - mean * mean;
    rstd = rsqrtf(var + LN_EPS);
    __syncthreads();
}

// ------------------------------------------------------------------
// slots = mu + exp(logsigma)*noise ; q = LN(slots; g_sl,b_sl) @ Wq + bq
__global__ __launch_bounds__(128) void k_init(
        const float* __restrict__ noise, const float* __restrict__ mu,
        const float* __restrict__ logsigma,
        const float* __restrict__ Wq, const float* __restrict__ bq,
        const float* __restrict__ g_sl, const float* __restrict__ b_sl,
        float* __restrict__ slots, float* __restrict__ q) {
    int bk_ = blockIdx.x;          // 0..B*K-1
    int j = threadIdx.x;
    __shared__ float red[4];
    __shared__ float tmp[DD];
    float s = mu[j] + __expf(logsigma[j]) * noise[bk_ * DD + j];
    slots[bk_ * DD + j] = s;
    float m, rs;
    block_stats(s, m, rs, red);
    tmp[j] = (s - m) * rs * g_sl[j] + b_sl[j];
    __syncthreads();
    float qv = bq[j];
    for (int d = 0; d < DD; d++) qv += tmp[d] * Wq[d * DD + j];
    q[bk_ * DD + j] = qv;
}

// ------------------------------------------------------------------
// Per n-chunk: dots (q·k^T), softmax over K (in-register), denom partials,
// and partial updates (attn·v outer-product partial over the chunk).
__global__ __launch_bounds__(128) void k_attn(
        const float* __restrict__ kpt, const float* __restrict__ vp,
        const float* __restrict__ q,
        float* __restrict__ upart, float* __restrict__ dpart,
        float* __restrict__ out_s, int last) {
    int blk = blockIdx.x;
    int b  = blk >> 7;         // / NCH
    int ch = blk & (NCH - 1);
    int n0 = ch * NCH_SZ;
    int t  = threadIdx.x;

    __shared__ float attn_lds[KK][NCH_SZ];

    const float* qb = q + b * KK * DD;     // wave-uniform -> scalar loads
    float acc[KK];
    #pragma unroll
    for (int k = 0; k < KK; k++) acc[k] = 0.f;

    const float* kp = kpt + (size_t)b * DD * NN + n0 + t;
    for (int d = 0; d < DD; d++) {
        float kv = kp[(size_t)d * NN];
        #pragma unroll
        for (int k = 0; k < KK; k++) acc[k] += qb[k * DD + d] * kv;
    }

    const float scale = 0.08838834764831845f;   // D^-0.5
    float mx = acc[0] * scale;
    #pragma unroll
    for (int k = 1; k < KK; k++) mx = fmaxf(mx, acc[k] * scale);
    float sum = 0.f;
    #pragma unroll
    for (int k = 0; k < KK; k++) { acc[k] = __expf(acc[k] * scale - mx); sum += acc[k]; }
    float inv = 1.0f / sum;
    #pragma unroll
    for (int k = 0; k < KK; k++) {
        acc[k] *= inv;
        attn_lds[k][t] = acc[k];
    }
    if (last) {
        float* sp = out_s + ((size_t)b * NN + n0 + t) * KK;
        #pragma unroll
        for (int k = 0; k < KK; k++) sp[k] = acc[k];
    }
    __syncthreads();

    // denom partials (sum of attn over chunk) — 10 threads
    if (t < KK) {
        float s = 0.f;
        for (int n = 0; n < NCH_SZ; n++) s += attn_lds[t][n];
        dpart[((size_t)b * NCH + ch) * KK + t] = s;
    }

    // updates partial: thread t = output dim d
    float up[KK];
    #pragma unroll
    for (int k = 0; k < KK; k++) up[k] = 0.f;
    const float* vpp = vp + ((size_t)b * NN + n0) * DD + t;
    for (int n = 0; n < NCH_SZ; n++) {
        float vv = vpp[(size_t)n * DD];
        #pragma unroll
        for (int k = 0; k < KK; k++) up[k] += attn_lds[k][n] * vv;
    }
    float* ud = upart + ((size_t)b * NCH + ch) * KK * DD;
    #pragma unroll
    for (int k = 0; k < KK; k++) ud[k * DD + t] = up[k];
}

// ------------------------------------------------------------------
// Reduce partials -> updates; GRU cell; LN+MLP residual; next-iteration q.
__global__ __launch_bounds__(128) void k_slot(
        const float* __restrict__ upart, const float* __restrict__ dpart,
        const float* __restrict__ sumv,
        const float* __restrict__ WihT, const float* __restrict__ WhhT,
        const float* __restrict__ bih, const float* __restrict__ bhh,
        const float* __restrict__ W1, const float* __restrict__ b1,
        const float* __restrict__ W2, const float* __restrict__ b2,
        const float* __restrict__ Wq, const float* __restrict__ bq,
        const float* __restrict__ g_ff, const float* __restrict__ b_ff,
        const float* __restrict__ g_sl, const float* __restrict__ b_sl,
        float* __restrict__ slots, float* __restrict__ q,
        float* __restrict__ out_nf, float* __restrict__ out_adj, int last) {
    int blk = blockIdx.x;
    int b = blk / KK, k = blk % KK;
    int j = threadIdx.x;
    __shared__ float red[4];
    __shared__ float u_lds[DD], p_lds[DD], tmp[DD];

    float u = 0.f;
    const float* up = upart + (size_t)b * NCH * KK * DD + k * DD + j;
    for (int c = 0; c < NCH; c++) u += up[(size_t)c * KK * DD];

    float dsum = 0.f;
    const float* dp = dpart + (size_t)b * NCH * KK + k;
    for (int c = 0; c < NCH; c++) dsum += dp[c * KK];
    float denom = dsum + (float)NN * ATT_EPS;

    float upd = (u + ATT_EPS * sumv[b * DD + j]) / denom;
    float prev = slots[(b * KK + k) * DD + j];
    u_lds[j] = upd;
    p_lds[j] = prev;
    __syncthreads();

    float gir = bih[j], giz = bih[DD + j], gin = bih[2 * DD + j];
    float ghr = bhh[j], ghz = bhh[DD + j], ghn = bhh[2 * DD + j];
    for (int d = 0; d < DD; d++) {
        float ud = u_lds[d], pd = p_lds[d];
        const float* wi = WihT + d * 3 * DD + j;
        const float* wh = WhhT + d * 3 * DD + j;
        gir += ud * wi[0];
        giz += ud * wi[DD];
        gin += ud * wi[2 * DD];
        ghr += pd * wh[0];
        ghz += pd * wh[DD];
        ghn += pd * wh[2 * DD];
    }
    float r  = 1.f / (1.f + __expf(-(gir + ghr)));
    float z  = 1.f / (1.f + __expf(-(giz + ghz)));
    float nn_ = tanhf(gin + r * ghn);
    float snew = (1.f - z) * nn_ + z * prev;

    float m, rs;
    block_stats(snew, m, rs, red);
    tmp[j] = (snew - m) * rs * g_ff[j] + b_ff[j];
    __syncthreads();
    float h = b1[j];
    for (int d = 0; d < DD; d++) h += tmp[d] * W1[d * DD + j];
    h = fmaxf(h, 0.f);
    __syncthreads();
    tmp[j] = h;
    __syncthreads();
    float o = snew + b2[j];
    for (int d = 0; d < DD; d++) o += tmp[d] * W2[d * DD + j];
    slots[(b * KK + k) * DD + j] = o;

    // q for next iteration (harmless on last)
    block_stats(o, m, rs, red);
    tmp[j] = (o - m) * rs * g_sl[j] + b_sl[j];
    __syncthreads();
    float qv = bq[j];
    for (int d = 0; d < DD; d++) qv += tmp[d] * Wq[d * DD + j];
    q[(b * KK + k) * DD + j] = qv;

    if (last) {
        out_nf[(b * KK + k) * DD + j] = o;
        if (j < KK) out_adj[(b * KK + k) * KK + j] = 1.0f;
    }
}

// ------------------------------------------------------------------
extern "C" void kernel_launch(void* const* d_in, const int* in_sizes, int n_in,
                              void* d_out, int out_size, void* d_ws, size_t ws_size,
                              hipStream_t stream) {
    (void)in_sizes; (void)n_in; (void)out_size; (void)ws_size;
    const float* x        = (const float*)d_in[0];
    const float* noise    = (const float*)d_in[1];
    const float* mu       = (const float*)d_in[2];
    const float* logsigma = (const float*)d_in[3];
    const float* Wq  = (const float*)d_in[4];
    const float* bq  = (const float*)d_in[5];
    const float* Wk  = (const float*)d_in[6];
    const float* bk  = (const float*)d_in[7];
    const float* Wv  = (const float*)d_in[8];
    const float* bv  = (const float*)d_in[9];
    const float* Wih = (const float*)d_in[10];
    const float* Whh = (const float*)d_in[11];
    const float* bih = (const float*)d_in[12];
    const float* bhh = (const float*)d_in[13];
    const float* W1  = (const float*)d_in[14];
    const float* b1  = (const float*)d_in[15];
    const float* W2  = (const float*)d_in[16];
    const float* b2  = (const float*)d_in[17];
    const float* g_in = (const float*)d_in[18];
    const float* b_in = (const float*)d_in[19];
    const float* g_sl = (const float*)d_in[20];
    const float* b_sl = (const float*)d_in[21];
    const float* g_ff = (const float*)d_in[22];
    const float* b_ff = (const float*)d_in[23];

    float* w = (float*)d_ws;
    float* kpt   = w + OFF_KPT;
    float* vp    = w + OFF_VP;
    float* qbuf  = w + OFF_Q;
    float* slots = w + OFF_SLOTS;
    float* upart = w + OFF_UPART;
    float* dpart = w + OFF_DPART;
    float* svp   = w + OFF_SVP;
    float* sumv  = w + OFF_SUMV;
    float* WihT  = w + OFF_WIHT;
    float* WhhT  = w + OFF_WHHT;

    float* out_nf  = (float*)d_out;                       // [B,K,D]
    float* out_adj = out_nf + BB * KK * DD;               // [B,K,K]
    float* out_s   = out_adj + BB * KK * KK;              // [B,N,K]

    k_transpose<<<192, 256, 0, stream>>>(Wih, Whh, WihT, WhhT);
    k_ln_kv<<<BB * NN / KV_R, 128, 0, stream>>>(x, Wk, bk, Wv, bv, g_in, b_in,
                                                kpt, vp, svp);
    k_sumv<<<BB, 128, 0, stream>>>(svp, sumv);
    k_init<<<BB * KK, 128, 0, stream>>>(noise, mu, logsigma, Wq, bq, g_sl, b_sl,
                                        slots, qbuf);

    for (int it = 0; it < N_ITERS; it++) {
        int last = (it == N_ITERS - 1) ? 1 : 0;
        k_attn<<<BB * NCH, 128, 0, stream>>>(kpt, vp, qbuf, upart, dpart, out_s, last);
        k_slot<<<BB * KK, 128, 0, stream>>>(upart, dpart, sumv, WihT, WhhT,
                                            bih, bhh, W1, b1, W2, b2, Wq, bq,
                                            g_ff, b_ff, g_sl, b_sl,
                                            slots, qbuf, out_nf, out_adj, last);
    }
}

// Round 5
// 418.760 us; speedup vs baseline: 1.3165x; 1.3165x over previous
//
#include <hip/hip_runtime.h>
#include <cstdint>

#define BB 8
#define NN 16384
#define DD 128
#define KK 10
#define N_ITERS 7
#define LN_EPS 1e-5f
#define ATT_EPS 1e-8f

#define LNR 64                 // rows per ln_kv block
#define LNCH (NN / LNR)        // 256 chunks per batch
#define NCH_SZ 128
#define NCH (NN / NCH_SZ)      // 128 chunks per batch

typedef __attribute__((ext_vector_type(8))) short bf16x8;
typedef __attribute__((ext_vector_type(4))) float f32x4;

__device__ inline ushort f2bf(float f) {
    uint u = __builtin_bit_cast(uint, f);
    u += 0x7FFFu + ((u >> 16) & 1u);
    return (ushort)(u >> 16);
}
__device__ inline float bf2f(ushort u) {
    return __builtin_bit_cast(float, ((uint)u) << 16);
}

// ---- workspace layout (float units; bf16 arrays use 2 per float) ----
#define OFF_KPT   ((size_t)0)                               // ushort[BB*DD*NN]
#define OFF_VP    (OFF_KPT + (size_t)BB * DD * NN / 2)      // ushort[BB*NN*DD]
#define OFF_WKVF  (OFF_VP + (size_t)BB * DD * NN / 2)       // ushort[32768]
#define OFF_Q     (OFF_WKVF + 16384)
#define OFF_SLOTS (OFF_Q + (size_t)BB * KK * DD)
#define OFF_UPART (OFF_SLOTS + (size_t)BB * KK * DD)
#define OFF_DPART (OFF_UPART + (size_t)BB * NCH * KK * DD)
#define OFF_SVP   (OFF_DPART + (size_t)BB * NCH * KK)
#define OFF_SUMV  (OFF_SVP + (size_t)BB * LNCH * DD)
#define OFF_WIHT  (OFF_SUMV + (size_t)BB * DD)
#define OFF_WHHT  (OFF_WIHT + (size_t)3 * DD * DD)

// ------------------------------------------------------------------
// Prep: WihT/WhhT transposes (fp32) + Wkv fragment-order bf16 pack.
// WkvF layout: ((ct*4 + ks)*64 + lane)*8 + j holds B[k][col] with
// col = ct*16 + (lane&15), k = ks*32 + (lane>>4)*8 + j; cols 0-127 = Wk,
// 128-255 = Wv.
__global__ void k_prep(const float* __restrict__ Wih, const float* __restrict__ Whh,
                       const float* __restrict__ Wk, const float* __restrict__ Wv,
                       float* __restrict__ WihT, float* __restrict__ WhhT,
                       ushort* __restrict__ WkvF) {
    int idx = blockIdx.x * 256 + threadIdx.x;
    if (idx < 3 * DD * DD) {
        int d = idx / (3 * DD);
        int j = idx % (3 * DD);
        WihT[idx] = Wih[j * DD + d];
        WhhT[idx] = Whh[j * DD + d];
    } else if (idx < 3 * DD * DD + 32768) {
        int i = idx - 3 * DD * DD;
        int jj = i & 7, l = (i >> 3) & 63, ks = (i >> 9) & 3, ct = i >> 11;
        int col = ct * 16 + (l & 15);
        int kk2 = ks * 32 + (l >> 4) * 8 + jj;
        float wv = (col < DD) ? Wk[kk2 * DD + col] : Wv[kk2 * DD + col - DD];
        WkvF[i] = f2bf(wv);
    }
}

// ------------------------------------------------------------------
// Fused LayerNorm + K/V projection via MFMA. 256 threads / 64 rows.
// Outputs: kpt bf16 [B][D][N] (transposed), vp bf16 [B][N][D],
// svp partial column sums of v.
__global__ __launch_bounds__(256) void k_ln_kv(
        const float* __restrict__ x, const ushort* __restrict__ WkvF,
        const float* __restrict__ bk, const float* __restrict__ bv,
        const float* __restrict__ g_in, const float* __restrict__ b_in,
        ushort* __restrict__ kpt, ushort* __restrict__ vp,
        float* __restrict__ svp) {
    __shared__ ushort xA[LNR][136];     // A tile bf16, padded (272B rows)
    __shared__ ushort kst[DD][68];      // K stage [col][n]
    __shared__ ushort vst[LNR][136];    // V stage [n][col]

    int t = threadIdx.x;
    int blk = blockIdx.x;
    int b  = blk >> 8;          // / LNCH
    int ch = blk & (LNCH - 1);
    int n0 = ch * LNR;

    // ---- LN: thread (r = t>>2, p = t&3) owns 32 cols of row r ----
    {
        int r = t >> 2, p = t & 3;
        const float4* xr = (const float4*)(x + ((size_t)(b * NN + n0 + r)) * DD + p * 32);
        float4 xv[8];
        float s = 0.f, sq = 0.f;
        #pragma unroll
        for (int i = 0; i < 8; i++) {
            xv[i] = xr[i];
            s  += xv[i].x + xv[i].y + xv[i].z + xv[i].w;
            sq += xv[i].x * xv[i].x + xv[i].y * xv[i].y +
                  xv[i].z * xv[i].z + xv[i].w * xv[i].w;
        }
        s  += __shfl_xor(s, 1);  sq += __shfl_xor(sq, 1);
        s  += __shfl_xor(s, 2);  sq += __shfl_xor(sq, 2);
        float mean = s * (1.0f / DD);
        float var  = sq * (1.0f / DD) - mean * mean;
        float rstd = rsqrtf(var + LN_EPS);
        #pragma unroll
        for (int i = 0; i < 8; i++) {
            int c0 = p * 32 + i * 4;
            ushort4 uv;
            uv.x = f2bf((xv[i].x - mean) * rstd * g_in[c0 + 0] + b_in[c0 + 0]);
            uv.y = f2bf((xv[i].y - mean) * rstd * g_in[c0 + 1] + b_in[c0 + 1]);
            uv.z = f2bf((xv[i].z - mean) * rstd * g_in[c0 + 2] + b_in[c0 + 2]);
            uv.w = f2bf((xv[i].w - mean) * rstd * g_in[c0 + 3] + b_in[c0 + 3]);
            *(ushort4*)&xA[r][c0] = uv;
        }
    }
    __syncthreads();

    // ---- MFMA: wave w handles coltiles 4w..4w+3 over all 4 rowtiles ----
    int w = t >> 6, l = t & 63;
    int lc = l & 15, lg = l >> 4;

    bf16x8 bfr[4][4];
    #pragma unroll
    for (int ci = 0; ci < 4; ci++)
        #pragma unroll
        for (int ks = 0; ks < 4; ks++) {
            int ct = w * 4 + ci;
            bfr[ci][ks] = *(const bf16x8*)(WkvF + ((size_t)((ct * 4 + ks) * 64 + l)) * 8);
        }

    f32x4 acc[4][4];
    #pragma unroll
    for (int rt = 0; rt < 4; rt++)
        #pragma unroll
        for (int ci = 0; ci < 4; ci++) acc[rt][ci] = (f32x4){0.f, 0.f, 0.f, 0.f};

    #pragma unroll
    for (int rt = 0; rt < 4; rt++) {
        bf16x8 afr[4];
        #pragma unroll
        for (int ks = 0; ks < 4; ks++)
            afr[ks] = *(const bf16x8*)&xA[rt * 16 + lc][ks * 32 + lg * 8];
        #pragma unroll
        for (int ci = 0; ci < 4; ci++)
            #pragma unroll
            for (int ks = 0; ks < 4; ks++)
                acc[rt][ci] = __builtin_amdgcn_mfma_f32_16x16x32_bf16(
                    afr[ks], bfr[ci][ks], acc[rt][ci], 0, 0, 0);
    }

    // ---- epilogue: bias add, stage to LDS ----
    #pragma unroll
    for (int rt = 0; rt < 4; rt++) {
        #pragma unroll
        for (int ci = 0; ci < 4; ci++) {
            int ct  = w * 4 + ci;
            int col = ct * 16 + lc;                 // 0..255
            float bias = (col < DD) ? bk[col] : bv[col - DD];
            int nloc = rt * 16 + lg * 4;
            if (col < DD) {
                ushort4 kv4;
                kv4.x = f2bf(acc[rt][ci][0] + bias);
                kv4.y = f2bf(acc[rt][ci][1] + bias);
                kv4.z = f2bf(acc[rt][ci][2] + bias);
                kv4.w = f2bf(acc[rt][ci][3] + bias);
                *(ushort4*)&kst[col][nloc] = kv4;
            } else {
                #pragma unroll
                for (int i = 0; i < 4; i++)
                    vst[nloc + i][col - DD] = f2bf(acc[rt][ci][i] + bias);
            }
        }
    }
    __syncthreads();

    // ---- coalesced writes ----
    {   // kpt: thread t -> col c = t>>1, half h = t&1 (32 n each)
        int c = t >> 1, h = t & 1;
        const ushort4* src = (const ushort4*)&kst[c][h * 32];
        ushort* dstp = kpt + ((size_t)(b * DD + c)) * NN + n0 + h * 32;
        #pragma unroll
        for (int j = 0; j < 8; j++) ((ushort4*)dstp)[j] = src[j];
    }
    {   // vp: thread t -> row r = t>>2, quarter q4 = t&3 (32 cols each)
        int r = t >> 2, q4 = t & 3;
        const uint4* src = (const uint4*)&vst[r][q4 * 32];
        uint4* dstp = (uint4*)(vp + ((size_t)(b * NN + n0 + r)) * DD + q4 * 32);
        #pragma unroll
        for (int j = 0; j < 4; j++) dstp[j] = src[j];
    }
    if (t < DD) {   // svp partial column sums of v
        float sv = 0.f;
        #pragma unroll 8
        for (int r = 0; r < LNR; r++) sv += bf2f(vst[r][t]);
        svp[((size_t)(b * LNCH + ch)) * DD + t] = sv;
    }
}

// ------------------------------------------------------------------
__global__ __launch_bounds__(128) void k_sumv(const float* __restrict__ svp,
                                              float* __restrict__ sumv) {
    int b = blockIdx.x, c = threadIdx.x;
    float s = 0.f;
    for (int cb = 0; cb < LNCH; cb++) s += svp[((size_t)(b * LNCH + cb)) * DD + c];
    sumv[b * DD + c] = s;
}

// ------------------------------------------------------------------
__device__ inline void block_stats(float v, float& mean, float& rstd, float* red) {
    float s = v, sq = v * v;
    #pragma unroll
    for (int o = 32; o > 0; o >>= 1) {
        s  += __shfl_down(s, o, 64);
        sq += __shfl_down(sq, o, 64);
    }
    int lane = threadIdx.x & 63, w = threadIdx.x >> 6;
    if (lane == 0) { red[w * 2] = s; red[w * 2 + 1] = sq; }
    __syncthreads();
    float S = red[0] + red[2], SQ = red[1] + red[3];
    mean = S * (1.0f / DD);
    float var = SQ * (1.0f / DD) - mean * mean;
    rstd = rsqrtf(var + LN_EPS);
    __syncthreads();
}

// ------------------------------------------------------------------
__global__ __launch_bounds__(128) void k_init(
        const float* __restrict__ noise, const float* __restrict__ mu,
        const float* __restrict__ logsigma,
        const float* __restrict__ Wq, const float* __restrict__ bq,
        const float* __restrict__ g_sl, const float* __restrict__ b_sl,
        float* __restrict__ slots, float* __restrict__ q) {
    int bk_ = blockIdx.x;
    int j = threadIdx.x;
    __shared__ float red[4];
    __shared__ float tmp[DD];
    float s = mu[j] + __expf(logsigma[j]) * noise[bk_ * DD + j];
    slots[bk_ * DD + j] = s;
    float m, rs;
    block_stats(s, m, rs, red);
    tmp[j] = (s - m) * rs * g_sl[j] + b_sl[j];
    __syncthreads();
    float qv = bq[j];
    for (int d = 0; d < DD; d++) qv += tmp[d] * Wq[d * DD + j];
    q[bk_ * DD + j] = qv;
}

// ------------------------------------------------------------------
// Per n-chunk: dots (q·k^T, bf16 k), softmax over K, denom partials via
// shfl, partial updates (attn·v, bf16 v).
__global__ __launch_bounds__(128) void k_attn(
        const ushort* __restrict__ kpt, const ushort* __restrict__ vp,
        const float* __restrict__ q,
        float* __restrict__ upart, float* __restrict__ dpart,
        float* __restrict__ out_s, int last) {
    int blk = blockIdx.x;
    int b  = blk >> 7;
    int ch = blk & (NCH - 1);
    int n0 = ch * NCH_SZ;
    int t  = threadIdx.x;

    __shared__ float attn_t[NCH_SZ][12];   // [n][k], padded to 12
    __shared__ float red2[2][16];

    const float* qg = q + (size_t)b * KK * DD;   // wave-uniform -> scalar loads

    float acc[KK];
    #pragma unroll
    for (int k = 0; k < KK; k++) acc[k] = 0.f;

    const ushort* kp = kpt + (size_t)b * DD * NN + n0 + t;
    for (int d = 0; d < DD; d++) {
        float kv = bf2f(kp[(size_t)d * NN]);
        #pragma unroll
        for (int k = 0; k < KK; k++) acc[k] += qg[k * DD + d] * kv;
    }

    const float scale = 0.08838834764831845f;   // D^-0.5
    float mx = acc[0] * scale;
    #pragma unroll
    for (int k = 1; k < KK; k++) mx = fmaxf(mx, acc[k] * scale);
    float sum = 0.f;
    #pragma unroll
    for (int k = 0; k < KK; k++) { acc[k] = __expf(acc[k] * scale - mx); sum += acc[k]; }
    float inv = 1.0f / sum;
    #pragma unroll
    for (int k = 0; k < KK; k++) {
        acc[k] *= inv;
        attn_t[t][k] = acc[k];
    }
    // denom partials: shfl-reduce per k across the 128 threads
    #pragma unroll
    for (int k = 0; k < KK; k++) {
        float v = acc[k];
        #pragma unroll
        for (int o = 32; o > 0; o >>= 1) v += __shfl_xor(v, o);
        if ((t & 63) == 0) red2[t >> 6][k] = v;
    }
    __syncthreads();
    if (t < KK) dpart[((size_t)b * NCH + ch) * KK + t] = red2[0][t] + red2[1][t];

    if (last) {
        float* sp = out_s + ((size_t)(b * NN + n0)) * KK;
        for (int j = t; j < NCH_SZ * KK; j += 128) {
            int n = j / KK, kk2 = j - n * KK;
            sp[j] = attn_t[n][kk2];
        }
    }

    // updates partial: thread t = output dim d
    float up[KK];
    #pragma unroll
    for (int k = 0; k < KK; k++) up[k] = 0.f;
    const ushort* vpp = vp + ((size_t)(b * NN + n0)) * DD + t;
    for (int n = 0; n < NCH_SZ; n++) {
        float vv = bf2f(vpp[(size_t)n * DD]);
        const float* at = &attn_t[n][0];
        float4 a0 = *(const float4*)(at);
        float4 a1 = *(const float4*)(at + 4);
        float2 a2 = *(const float2*)(at + 8);
        up[0] += a0.x * vv;  up[1] += a0.y * vv;
        up[2] += a0.z * vv;  up[3] += a0.w * vv;
        up[4] += a1.x * vv;  up[5] += a1.y * vv;
        up[6] += a1.z * vv;  up[7] += a1.w * vv;
        up[8] += a2.x * vv;  up[9] += a2.y * vv;
    }
    float* ud = upart + ((size_t)b * NCH + ch) * KK * DD;
    #pragma unroll
    for (int k = 0; k < KK; k++) ud[k * DD + t] = up[k];
}

// ------------------------------------------------------------------
// Reduce partials -> updates; GRU; LN+MLP residual; next q. 384 threads.
__global__ __launch_bounds__(384) void k_slot(
        const float* __restrict__ upart, const float* __restrict__ dpart,
        const float* __restrict__ sumv,
        const float* __restrict__ WihT, const float* __restrict__ WhhT,
        const float* __restrict__ bih, const float* __restrict__ bhh,
        const float* __restrict__ W1, const float* __restrict__ b1,
        const float* __restrict__ W2, const float* __restrict__ b2,
        const float* __restrict__ Wq, const float* __restrict__ bq,
        const float* __restrict__ g_ff, const float* __restrict__ b_ff,
        const float* __restrict__ g_sl, const float* __restrict__ b_sl,
        float* __restrict__ slots, float* __restrict__ q,
        float* __restrict__ out_nf, float* __restrict__ out_adj, int last) {
    int blk = blockIdx.x;
    int b = blk / KK, kslot = blk % KK;
    int t = threadIdx.x;
    __shared__ float u_lds[DD], p_lds[DD], tmp[DD];
    __shared__ float gi_lds[3 * DD], gh_lds[3 * DD];
    __shared__ float upr[3][DD];
    __shared__ float red[8];

    // --- u partial reduce (3-way split over 128 chunks) ---
    {
        int j = t & 127, g = t >> 7;
        int c0 = g * 43, c1 = (g == 2) ? NCH : c0 + 43;
        float u = 0.f;
        const float* up = upart + (size_t)b * NCH * KK * DD + kslot * DD + j;
        for (int c = c0; c < c1; c++) u += up[(size_t)c * KK * DD];
        upr[g][j] = u;
    }
    // --- denom: 64 threads, 2 chunks each, shfl reduce ---
    {
        float dsv = 0.f;
        if (t < 64) {
            const float* dp = dpart + (size_t)b * NCH * KK + kslot;
            dsv = dp[(size_t)(2 * t) * KK] + dp[(size_t)(2 * t + 1) * KK];
        }
        #pragma unroll
        for (int o = 32; o > 0; o >>= 1) dsv += __shfl_xor(dsv, o);
        if (t == 0) red[6] = dsv + (float)NN * ATT_EPS;
    }
    __syncthreads();

    float snew = 0.f, prev = 0.f;
    if (t < DD) {
        float u = upr[0][t] + upr[1][t] + upr[2][t];
        float upd = (u + ATT_EPS * sumv[b * DD + t]) / red[6];
        prev = slots[(b * KK + kslot) * DD + t];
        u_lds[t] = upd;
        p_lds[t] = prev;
    }
    __syncthreads();

    // --- gi/gh: one column per thread (384 columns) ---
    {
        float gi = bih[t], gh = bhh[t];
        for (int d4 = 0; d4 < DD / 4; d4++) {
            float4 uv = *(const float4*)&u_lds[d4 * 4];
            float4 pv = *(const float4*)&p_lds[d4 * 4];
            const float* wi = WihT + (size_t)(d4 * 4) * 3 * DD + t;
            const float* wh = WhhT + (size_t)(d4 * 4) * 3 * DD + t;
            gi += uv.x * wi[0] + uv.y * wi[3 * DD] + uv.z * wi[6 * DD] + uv.w * wi[9 * DD];
            gh += pv.x * wh[0] + pv.y * wh[3 * DD] + pv.z * wh[6 * DD] + pv.w * wh[9 * DD];
        }
        gi_lds[t] = gi;
        gh_lds[t] = gh;
    }
    __syncthreads();

    if (t < DD) {
        float r = 1.f / (1.f + __expf(-(gi_lds[t] + gh_lds[t])));
        float z = 1.f / (1.f + __expf(-(gi_lds[DD + t] + gh_lds[DD + t])));
        float nn_ = tanhf(gi_lds[2 * DD + t] + r * gh_lds[2 * DD + t]);
        snew = (1.f - z) * nn_ + z * prev;
    }
    // --- LN(snew) over 128 active threads ---
    {
        float s_ = (t < DD) ? snew : 0.f, sq_ = s_ * s_;
        #pragma unroll
        for (int o = 32; o > 0; o >>= 1) { s_ += __shfl_xor(s_, o); sq_ += __shfl_xor(sq_, o); }
        if (t < DD && (t & 63) == 0) { red[(t >> 6) * 2] = s_; red[(t >> 6) * 2 + 1] = sq_; }
    }
    __syncthreads();
    if (t < DD) {
        float mean = (red[0] + red[2]) * (1.0f / DD);
        float var  = (red[1] + red[3]) * (1.0f / DD) - mean * mean;
        float rstd = rsqrtf(var + LN_EPS);
        tmp[t] = (snew - mean) * rstd * g_ff[t] + b_ff[t];
    }
    __syncthreads();
    float h = 0.f;
    if (t < DD) {
        h = b1[t];
        for (int d4 = 0; d4 < DD / 4; d4++) {
            float4 tv = *(const float4*)&tmp[d4 * 4];
            const float* wp = W1 + (size_t)(d4 * 4) * DD + t;
            h += tv.x * wp[0] + tv.y * wp[DD] + tv.z * wp[2 * DD] + tv.w * wp[3 * DD];
        }
        h = fmaxf(h, 0.f);
    }
    __syncthreads();
    if (t < DD) tmp[t] = h;
    __syncthreads();
    float o = 0.f;
    if (t < DD) {
        o = snew + b2[t];
        for (int d4 = 0; d4 < DD / 4; d4++) {
            float4 tv = *(const float4*)&tmp[d4 * 4];
            const float* wp = W2 + (size_t)(d4 * 4) * DD + t;
            o += tv.x * wp[0] + tv.y * wp[DD] + tv.z * wp[2 * DD] + tv.w * wp[3 * DD];
        }
        slots[(b * KK + kslot) * DD + t] = o;
    }
    // --- LN(o) + q for next iteration ---
    {
        float s_ = (t < DD) ? o : 0.f, sq_ = s_ * s_;
        #pragma unroll
        for (int o2 = 32; o2 > 0; o2 >>= 1) { s_ += __shfl_xor(s_, o2); sq_ += __shfl_xor(sq_, o2); }
        if (t < DD && (t & 63) == 0) { red[(t >> 6) * 2] = s_; red[(t >> 6) * 2 + 1] = sq_; }
    }
    __syncthreads();
    if (t < DD) {
        float mean = (red[0] + red[2]) * (1.0f / DD);
        float var  = (red[1] + red[3]) * (1.0f / DD) - mean * mean;
        float rstd = rsqrtf(var + LN_EPS);
        tmp[t] = (o - mean) * rstd * g_sl[t] + b_sl[t];
    }
    __syncthreads();
    if (t < DD) {
        float qv = bq[t];
        for (int d4 = 0; d4 < DD / 4; d4++) {
            float4 tv = *(const float4*)&tmp[d4 * 4];
            const float* wp = Wq + (size_t)(d4 * 4) * DD + t;
            qv += tv.x * wp[0] + tv.y * wp[DD] + tv.z * wp[2 * DD] + tv.w * wp[3 * DD];
        }
        q[(b * KK + kslot) * DD + t] = qv;
        if (last) {
            out_nf[(b * KK + kslot) * DD + t] = o;
            if (t < KK) out_adj[(b * KK + kslot) * KK + t] = 1.0f;
        }
    }
}

// ------------------------------------------------------------------
extern "C" void kernel_launch(void* const* d_in, const int* in_sizes, int n_in,
                              void* d_out, int out_size, void* d_ws, size_t ws_size,
                              hipStream_t stream) {
    (void)in_sizes; (void)n_in; (void)out_size; (void)ws_size;
    const float* x        = (const float*)d_in[0];
    const float* noise    = (const float*)d_in[1];
    const float* mu       = (const float*)d_in[2];
    const float* logsigma = (const float*)d_in[3];
    const float* Wq  = (const float*)d_in[4];
    const float* bq  = (const float*)d_in[5];
    const float* Wk  = (const float*)d_in[6];
    const float* bk  = (const float*)d_in[7];
    const float* Wv  = (const float*)d_in[8];
    const float* bv  = (const float*)d_in[9];
    const float* Wih = (const float*)d_in[10];
    const float* Whh = (const float*)d_in[11];
    const float* bih = (const float*)d_in[12];
    const float* bhh = (const float*)d_in[13];
    const float* W1  = (const float*)d_in[14];
    const float* b1  = (const float*)d_in[15];
    const float* W2  = (const float*)d_in[16];
    const float* b2  = (const float*)d_in[17];
    const float* g_in = (const float*)d_in[18];
    const float* b_in = (const float*)d_in[19];
    const float* g_sl = (const float*)d_in[20];
    const float* b_sl = (const float*)d_in[21];
    const float* g_ff = (const float*)d_in[22];
    const float* b_ff = (const float*)d_in[23];

    float* w = (float*)d_ws;
    ushort* kpt  = (ushort*)(w + OFF_KPT);
    ushort* vp   = (ushort*)(w + OFF_VP);
    ushort* WkvF = (ushort*)(w + OFF_WKVF);
    float* qbuf  = w + OFF_Q;
    float* slots = w + OFF_SLOTS;
    float* upart = w + OFF_UPART;
    float* dpart = w + OFF_DPART;
    float* svp   = w + OFF_SVP;
    float* sumv  = w + OFF_SUMV;
    float* WihT  = w + OFF_WIHT;
    float* WhhT  = w + OFF_WHHT;

    float* out_nf  = (float*)d_out;                       // [B,K,D]
    float* out_adj = out_nf + BB * KK * DD;               // [B,K,K]
    float* out_s   = out_adj + BB * KK * KK;              // [B,N,K]

    k_prep<<<320, 256, 0, stream>>>(Wih, Whh, Wk, Wv, WihT, WhhT, WkvF);
    k_ln_kv<<<BB * LNCH, 256, 0, stream>>>(x, WkvF, bk, bv, g_in, b_in,
                                           kpt, vp, svp);
    k_sumv<<<BB, 128, 0, stream>>>(svp, sumv);
    k_init<<<BB * KK, 128, 0, stream>>>(noise, mu, logsigma, Wq, bq, g_sl, b_sl,
                                        slots, qbuf);

    for (int it = 0; it < N_ITERS; it++) {
        int last = (it == N_ITERS - 1) ? 1 : 0;
        k_attn<<<BB * NCH, 128, 0, stream>>>(kpt, vp, qbuf, upart, dpart, out_s, last);
        k_slot<<<BB * KK, 384, 0, stream>>>(upart, dpart, sumv, WihT, WhhT,
                                            bih, bhh, W1, b1, W2, b2, Wq, bq,
                                            g_ff, b_ff, g_sl, b_sl,
                                            slots, qbuf, out_nf, out_adj, last);
    }
}

// Round 6
// 315.524 us; speedup vs baseline: 1.7472x; 1.3272x over previous
//
#include <hip/hip_runtime.h>
#include <cstdint>

#define BB 8
#define NN 16384
#define DD 128
#define KK 10
#define N_ITERS 7
#define LN_EPS 1e-5f
#define ATT_EPS 1e-8f

#define LNR 32                 // rows per ln_kv block
#define LNCH (NN / LNR)        // 512 chunks per batch
#define NB 128                 // n per attn block
#define NCH (NN / NB)          // 128 chunks per batch

typedef __attribute__((ext_vector_type(8))) short bf16x8;
typedef __attribute__((ext_vector_type(4))) float f32x4;

__device__ inline ushort f2bf(float f) {
    uint u = __builtin_bit_cast(uint, f);
    u += 0x7FFFu + ((u >> 16) & 1u);
    return (ushort)(u >> 16);
}
__device__ inline float bf2f(ushort u) {
    return __builtin_bit_cast(float, ((uint)u) << 16);
}

// ---- workspace layout (float units; bf16 arrays use 2 per float) ----
// kR: K row-major [B][N][D] bf16 ; vT: V transposed [B][D][N] bf16
#define OFF_KR    ((size_t)0)
#define OFF_VT    (OFF_KR + (size_t)BB * NN * DD / 2)
#define OFF_WKVF  (OFF_VT + (size_t)BB * DD * NN / 2)       // ushort[32768]
#define OFF_Q     (OFF_WKVF + 16384)
#define OFF_SLOTS (OFF_Q + (size_t)BB * KK * DD)
#define OFF_UPART (OFF_SLOTS + (size_t)BB * KK * DD)
#define OFF_DPART (OFF_UPART + (size_t)BB * NCH * KK * DD)
#define OFF_SVP   (OFF_DPART + (size_t)BB * NCH * KK)
#define OFF_SUMV  (OFF_SVP + (size_t)BB * LNCH * DD)
#define OFF_WIHT  (OFF_SUMV + (size_t)BB * DD)
#define OFF_WHHT  (OFF_WIHT + (size_t)3 * DD * DD)

// ------------------------------------------------------------------
// Prep: WihT/WhhT transposes (fp32) + Wkv fragment-order bf16 pack.
// WkvF: ((ct*4+ks)*64+lane)*8+j holds B[k][col], col=ct*16+(lane&15),
// k=ks*32+(lane>>4)*8+j; cols 0-127 = Wk, 128-255 = Wv.  (HW-verified r5)
__global__ void k_prep(const float* __restrict__ Wih, const float* __restrict__ Whh,
                       const float* __restrict__ Wk, const float* __restrict__ Wv,
                       float* __restrict__ WihT, float* __restrict__ WhhT,
                       ushort* __restrict__ WkvF) {
    int idx = blockIdx.x * 256 + threadIdx.x;
    if (idx < 3 * DD * DD) {
        int d = idx / (3 * DD);
        int j = idx % (3 * DD);
        WihT[idx] = Wih[j * DD + d];
        WhhT[idx] = Whh[j * DD + d];
    } else if (idx < 3 * DD * DD + 32768) {
        int i = idx - 3 * DD * DD;
        int jj = i & 7, l = (i >> 3) & 63, ks = (i >> 9) & 3, ct = i >> 11;
        int col = ct * 16 + (l & 15);
        int kk2 = ks * 32 + (l >> 4) * 8 + jj;
        float wv = (col < DD) ? Wk[kk2 * DD + col] : Wv[kk2 * DD + col - DD];
        WkvF[i] = f2bf(wv);
    }
}

// ------------------------------------------------------------------
// Fused LayerNorm + K/V projection via MFMA. 256 threads / 32 rows.
// Outputs: kR bf16 [B][N][D] (row-major), vT bf16 [B][D][N] (transposed),
// svp partial column sums of v.  LDS ~27 KB -> 6 blocks/CU.
__global__ __launch_bounds__(256) void k_ln_kv(
        const float* __restrict__ x, const ushort* __restrict__ WkvF,
        const float* __restrict__ bk, const float* __restrict__ bv,
        const float* __restrict__ g_in, const float* __restrict__ b_in,
        ushort* __restrict__ kR, ushort* __restrict__ vT,
        float* __restrict__ svp) {
    __shared__ ushort xA[LNR][136];     // A tile bf16 (272B rows, 16B-aligned)
    __shared__ ushort kstR[LNR][136];   // K stage [n][col]
    __shared__ ushort vstT[DD][40];     // V stage [col][n] (80B rows, 16B-aligned)

    int t = threadIdx.x;
    int blk = blockIdx.x;
    int b  = blk >> 9;          // / LNCH
    int ch = blk & (LNCH - 1);
    int n0 = ch * LNR;

    // ---- LN: thread (r = t>>3, p = t&7) owns 16 cols of row r ----
    {
        int r = t >> 3, p = t & 7;
        const float4* xr = (const float4*)(x + ((size_t)(b * NN + n0 + r)) * DD + p * 16);
        float4 xv[4];
        float s = 0.f, sq = 0.f;
        #pragma unroll
        for (int i = 0; i < 4; i++) {
            xv[i] = xr[i];
            s  += xv[i].x + xv[i].y + xv[i].z + xv[i].w;
            sq += xv[i].x * xv[i].x + xv[i].y * xv[i].y +
                  xv[i].z * xv[i].z + xv[i].w * xv[i].w;
        }
        s += __shfl_xor(s, 1);  sq += __shfl_xor(sq, 1);
        s += __shfl_xor(s, 2);  sq += __shfl_xor(sq, 2);
        s += __shfl_xor(s, 4);  sq += __shfl_xor(sq, 4);
        float mean = s * (1.0f / DD);
        float var  = sq * (1.0f / DD) - mean * mean;
        float rstd = rsqrtf(var + LN_EPS);
        #pragma unroll
        for (int i = 0; i < 4; i++) {
            int c0 = p * 16 + i * 4;
            ushort4 uv;
            uv.x = f2bf((xv[i].x - mean) * rstd * g_in[c0 + 0] + b_in[c0 + 0]);
            uv.y = f2bf((xv[i].y - mean) * rstd * g_in[c0 + 1] + b_in[c0 + 1]);
            uv.z = f2bf((xv[i].z - mean) * rstd * g_in[c0 + 2] + b_in[c0 + 2]);
            uv.w = f2bf((xv[i].w - mean) * rstd * g_in[c0 + 3] + b_in[c0 + 3]);
            *(ushort4*)&xA[r][c0] = uv;
        }
    }
    __syncthreads();

    // ---- MFMA: wave w handles coltiles 4w..4w+3 over 2 rowtiles ----
    int w = t >> 6, l = t & 63;
    int lc = l & 15, lg = l >> 4;

    bf16x8 bfr[4][4];
    #pragma unroll
    for (int ci = 0; ci < 4; ci++)
        #pragma unroll
        for (int ks = 0; ks < 4; ks++) {
            int ct = w * 4 + ci;
            bfr[ci][ks] = *(const bf16x8*)(WkvF + ((size_t)((ct * 4 + ks) * 64 + l)) * 8);
        }

    f32x4 acc[2][4];
    #pragma unroll
    for (int rt = 0; rt < 2; rt++)
        #pragma unroll
        for (int ci = 0; ci < 4; ci++) acc[rt][ci] = (f32x4){0.f, 0.f, 0.f, 0.f};

    #pragma unroll
    for (int rt = 0; rt < 2; rt++) {
        bf16x8 afr[4];
        #pragma unroll
        for (int ks = 0; ks < 4; ks++)
            afr[ks] = *(const bf16x8*)&xA[rt * 16 + lc][ks * 32 + lg * 8];
        #pragma unroll
        for (int ci = 0; ci < 4; ci++)
            #pragma unroll
            for (int ks = 0; ks < 4; ks++)
                acc[rt][ci] = __builtin_amdgcn_mfma_f32_16x16x32_bf16(
                    afr[ks], bfr[ci][ks], acc[rt][ci], 0, 0, 0);
    }

    // ---- epilogue: bias add, stage to LDS ----
    #pragma unroll
    for (int rt = 0; rt < 2; rt++) {
        #pragma unroll
        for (int ci = 0; ci < 4; ci++) {
            int ct  = w * 4 + ci;
            int col = ct * 16 + lc;                 // 0..255
            float bias = (col < DD) ? bk[col] : bv[col - DD];
            int nloc = rt * 16 + lg * 4;
            if (col < DD) {                         // K: row-major stage
                #pragma unroll
                for (int i = 0; i < 4; i++)
                    kstR[nloc + i][col] = f2bf(acc[rt][ci][i] + bias);
            } else {                                // V: transposed stage
                ushort4 v4;
                v4.x = f2bf(acc[rt][ci][0] + bias);
                v4.y = f2bf(acc[rt][ci][1] + bias);
                v4.z = f2bf(acc[rt][ci][2] + bias);
                v4.w = f2bf(acc[rt][ci][3] + bias);
                *(ushort4*)&vstT[col - DD][nloc] = v4;
            }
        }
    }
    __syncthreads();

    // ---- coalesced writes ----
    {   // kR: thread t -> row r = t>>3, octet o = t&7 (16 cols = 32B)
        int r = t >> 3, o = t & 7;
        const uint4* src = (const uint4*)&kstR[r][o * 16];
        uint4* dst = (uint4*)(kR + ((size_t)(b * NN + n0 + r)) * DD + o * 16);
        dst[0] = src[0];
        dst[1] = src[1];
    }
    {   // vT: thread t -> col c = t>>1, half h = t&1 (16 n = 32B)
        int c = t >> 1, h = t & 1;
        const uint4* src = (const uint4*)&vstT[c][h * 16];
        uint4* dst = (uint4*)(vT + ((size_t)(b * DD + c)) * NN + n0 + h * 16);
        dst[0] = src[0];
        dst[1] = src[1];
    }
    if (t < DD) {   // svp partial column sums of v
        float sv = 0.f;
        #pragma unroll 8
        for (int r = 0; r < LNR; r++) sv += bf2f(vstT[t][r]);
        svp[((size_t)(b * LNCH + ch)) * DD + t] = sv;
    }
}

// ------------------------------------------------------------------
__global__ __launch_bounds__(128) void k_sumv(const float* __restrict__ svp,
                                              float* __restrict__ sumv) {
    int b = blockIdx.x, c = threadIdx.x;
    float s = 0.f;
    for (int cb = 0; cb < LNCH; cb++) s += svp[((size_t)(b * LNCH + cb)) * DD + c];
    sumv[b * DD + c] = s;
}

// ------------------------------------------------------------------
__device__ inline void block_stats(float v, float& mean, float& rstd, float* red) {
    float s = v, sq = v * v;
    #pragma unroll
    for (int o = 32; o > 0; o >>= 1) {
        s  += __shfl_down(s, o, 64);
        sq += __shfl_down(sq, o, 64);
    }
    int lane = threadIdx.x & 63, w = threadIdx.x >> 6;
    if (lane == 0) { red[w * 2] = s; red[w * 2 + 1] = sq; }
    __syncthreads();
    float S = red[0] + red[2], SQ = red[1] + red[3];
    mean = S * (1.0f / DD);
    float var = SQ * (1.0f / DD) - mean * mean;
    rstd = rsqrtf(var + LN_EPS);
    __syncthreads();
}

// ------------------------------------------------------------------
__global__ __launch_bounds__(128) void k_init(
        const float* __restrict__ noise, const float* __restrict__ mu,
        const float* __restrict__ logsigma,
        const float* __restrict__ Wq, const float* __restrict__ bq,
        const float* __restrict__ g_sl, const float* __restrict__ b_sl,
        float* __restrict__ slots, float* __restrict__ q) {
    int bk_ = blockIdx.x;
    int j = threadIdx.x;
    __shared__ float red[4];
    __shared__ float tmp[DD];
    float s = mu[j] + __expf(logsigma[j]) * noise[bk_ * DD + j];
    slots[bk_ * DD + j] = s;
    float m, rs;
    block_stats(s, m, rs, red);
    tmp[j] = (s - m) * rs * g_sl[j] + b_sl[j];
    __syncthreads();
    float qv = bq[j];
    for (int d = 0; d < DD; d++) qv += tmp[d] * Wq[d * DD + j];
    q[bk_ * DD + j] = qv;
}

// ------------------------------------------------------------------
// MFMA attention iteration. 256 threads (4 waves), NB=128 n per block.
// dots^T:   C[n][slot] = K[n][:] . q[slot][:]   (A = K rows, B = q^T)
// softmax over slots (cols 0..9) per n via 16-lane shfl reduce.
// updates^T: C'[d][slot] = vT[d][:] . P[:][slot] (A = vT rows, B = P)
__global__ __launch_bounds__(256) void k_attn(
        const ushort* __restrict__ kR, const ushort* __restrict__ vT,
        const float* __restrict__ q,
        float* __restrict__ upart, float* __restrict__ dpart,
        float* __restrict__ out_s, int last) {
    __shared__ ushort qlds[16][136];   // q bf16, pre-scaled, rows 10-15 zero
    __shared__ ushort plds[NB][18];    // P bf16 [n][slot], pad 18
    __shared__ float red[4][16];

    int t = threadIdx.x;
    int blk = blockIdx.x;
    int b  = blk >> 7;
    int ch = blk & (NCH - 1);
    int n0 = ch * NB;
    int w = t >> 6, l = t & 63;
    int lc = l & 15, lg = l >> 4;

    const float scale = 0.08838834764831845f;   // D^-0.5
    for (int j = t; j < 16 * DD; j += 256) {
        int row = j >> 7, col = j & 127;
        float v = (row < KK) ? q[((size_t)b * KK + row) * DD + col] * scale : 0.f;
        qlds[row][col] = f2bf(v);
    }
    __syncthreads();

    // q B-frags: B[k=d][col=slot] -> qlds[lc][ks*32+lg*8+j]
    bf16x8 qb[4];
    #pragma unroll
    for (int ks = 0; ks < 4; ks++)
        qb[ks] = *(const bf16x8*)&qlds[lc][ks * 32 + lg * 8];

    float dsum = 0.f;
    bool valid = lc < KK;
    #pragma unroll
    for (int tt = 0; tt < 2; tt++) {
        int nt = w * 2 + tt;    // n-tile 0..7
        const ushort* kb = kR + ((size_t)(b * NN + n0 + nt * 16 + lc)) * DD + lg * 8;
        f32x4 acc = (f32x4){0.f, 0.f, 0.f, 0.f};
        #pragma unroll
        for (int ks = 0; ks < 4; ks++) {
            bf16x8 a = *(const bf16x8*)(kb + ks * 32);   // 16B coalesced
            acc = __builtin_amdgcn_mfma_f32_16x16x32_bf16(a, qb[ks], acc, 0, 0, 0);
        }
        // softmax per row (n); C layout: row=(l>>4)*4+r, col=slot=lc
        #pragma unroll
        for (int r = 0; r < 4; r++) {
            float v = acc[r];
            float m = valid ? v : -3.0e38f;
            m = fmaxf(m, __shfl_xor(m, 1));
            m = fmaxf(m, __shfl_xor(m, 2));
            m = fmaxf(m, __shfl_xor(m, 4));
            m = fmaxf(m, __shfl_xor(m, 8));
            float e = valid ? __expf(v - m) : 0.f;
            float s = e;
            s += __shfl_xor(s, 1);
            s += __shfl_xor(s, 2);
            s += __shfl_xor(s, 4);
            s += __shfl_xor(s, 8);
            float p = e / s;
            dsum += p;
            plds[nt * 16 + lg * 4 + r][lc] = f2bf(p);
        }
    }
    // denom partial: sum over this wave's 32 n, per slot (col)
    dsum += __shfl_xor(dsum, 16);
    dsum += __shfl_xor(dsum, 32);
    if (l < 16) red[w][l] = dsum;
    __syncthreads();

    if (t < KK)
        dpart[((size_t)b * NCH + ch) * KK + t] =
            red[0][t] + red[1][t] + red[2][t] + red[3][t];

    // P B-frags: B[k=n][col=slot] -> plds[ks*32+lg*8+j][lc]
    bf16x8 pb[4];
    #pragma unroll
    for (int ks = 0; ks < 4; ks++) {
        #pragma unroll
        for (int j = 0; j < 8; j++)
            pb[ks][j] = (short)plds[ks * 32 + lg * 8 + j][lc];
    }

    float* ud = upart + ((size_t)b * NCH + ch) * KK * DD;
    #pragma unroll
    for (int tt = 0; tt < 2; tt++) {
        int dt = w * 2 + tt;    // d-tile 0..7
        const ushort* vb = vT + ((size_t)(b * DD + dt * 16 + lc)) * NN + n0 + lg * 8;
        f32x4 uacc = (f32x4){0.f, 0.f, 0.f, 0.f};
        #pragma unroll
        for (int ks = 0; ks < 4; ks++) {
            bf16x8 a = *(const bf16x8*)(vb + ks * 32);   // 16B coalesced
            uacc = __builtin_amdgcn_mfma_f32_16x16x32_bf16(a, pb[ks], uacc, 0, 0, 0);
        }
        if (valid) {   // C' row = d local = lg*4+r, col = slot = lc
            float4 st = {uacc[0], uacc[1], uacc[2], uacc[3]};
            *(float4*)&ud[lc * DD + dt * 16 + lg * 4] = st;
        }
    }

    if (last) {
        for (int i = t; i < NB * KK; i += 256) {
            int n = i / KK, s2 = i - n * KK;
            out_s[((size_t)b * NN + n0 + n) * KK + s2] = bf2f(plds[n][s2]);
        }
    }
}

// ------------------------------------------------------------------
// Reduce partials -> updates; GRU; LN+MLP residual; next q. 384 threads.
__global__ __launch_bounds__(384) void k_slot(
        const float* __restrict__ upart, const float* __restrict__ dpart,
        const float* __restrict__ sumv,
        const float* __restrict__ WihT, const float* __restrict__ WhhT,
        const float* __restrict__ bih, const float* __restrict__ bhh,
        const float* __restrict__ W1, const float* __restrict__ b1,
        const float* __restrict__ W2, const float* __restrict__ b2,
        const float* __restrict__ Wq, const float* __restrict__ bq,
        const float* __restrict__ g_ff, const float* __restrict__ b_ff,
        const float* __restrict__ g_sl, const float* __restrict__ b_sl,
        float* __restrict__ slots, float* __restrict__ q,
        float* __restrict__ out_nf, float* __restrict__ out_adj, int last) {
    int blk = blockIdx.x;
    int b = blk / KK, kslot = blk % KK;
    int t = threadIdx.x;
    __shared__ float u_lds[DD], p_lds[DD], tmp[DD];
    __shared__ float gi_lds[3 * DD], gh_lds[3 * DD];
    __shared__ float upr[3][DD];
    __shared__ float red[8];

    // --- u partial reduce (3-way split over 128 chunks) ---
    {
        int j = t & 127, g = t >> 7;
        int c0 = g * 43, c1 = (g == 2) ? NCH : c0 + 43;
        float u = 0.f;
        const float* up = upart + (size_t)b * NCH * KK * DD + kslot * DD + j;
        for (int c = c0; c < c1; c++) u += up[(size_t)c * KK * DD];
        upr[g][j] = u;
    }
    // --- denom: 64 threads, 2 chunks each, shfl reduce ---
    {
        float dsv = 0.f;
        if (t < 64) {
            const float* dp = dpart + (size_t)b * NCH * KK + kslot;
            dsv = dp[(size_t)(2 * t) * KK] + dp[(size_t)(2 * t + 1) * KK];
        }
        #pragma unroll
        for (int o = 32; o > 0; o >>= 1) dsv += __shfl_xor(dsv, o);
        if (t == 0) red[6] = dsv + (float)NN * ATT_EPS;
    }
    __syncthreads();

    float snew = 0.f, prev = 0.f;
    if (t < DD) {
        float u = upr[0][t] + upr[1][t] + upr[2][t];
        float upd = (u + ATT_EPS * sumv[b * DD + t]) / red[6];
        prev = slots[(b * KK + kslot) * DD + t];
        u_lds[t] = upd;
        p_lds[t] = prev;
    }
    __syncthreads();

    // --- gi/gh: one column per thread (384 columns) ---
    {
        float gi = bih[t], gh = bhh[t];
        for (int d4 = 0; d4 < DD / 4; d4++) {
            float4 uv = *(const float4*)&u_lds[d4 * 4];
            float4 pv = *(const float4*)&p_lds[d4 * 4];
            const float* wi = WihT + (size_t)(d4 * 4) * 3 * DD + t;
            const float* wh = WhhT + (size_t)(d4 * 4) * 3 * DD + t;
            gi += uv.x * wi[0] + uv.y * wi[3 * DD] + uv.z * wi[6 * DD] + uv.w * wi[9 * DD];
            gh += pv.x * wh[0] + pv.y * wh[3 * DD] + pv.z * wh[6 * DD] + pv.w * wh[9 * DD];
        }
        gi_lds[t] = gi;
        gh_lds[t] = gh;
    }
    __syncthreads();

    if (t < DD) {
        float r = 1.f / (1.f + __expf(-(gi_lds[t] + gh_lds[t])));
        float z = 1.f / (1.f + __expf(-(gi_lds[DD + t] + gh_lds[DD + t])));
        float nn_ = tanhf(gi_lds[2 * DD + t] + r * gh_lds[2 * DD + t]);
        snew = (1.f - z) * nn_ + z * prev;
    }
    // --- LN(snew) over 128 active threads ---
    {
        float s_ = (t < DD) ? snew : 0.f, sq_ = s_ * s_;
        #pragma unroll
        for (int o = 32; o > 0; o >>= 1) { s_ += __shfl_xor(s_, o); sq_ += __shfl_xor(sq_, o); }
        if (t < DD && (t & 63) == 0) { red[(t >> 6) * 2] = s_; red[(t >> 6) * 2 + 1] = sq_; }
    }
    __syncthreads();
    if (t < DD) {
        float mean = (red[0] + red[2]) * (1.0f / DD);
        float var  = (red[1] + red[3]) * (1.0f / DD) - mean * mean;
        float rstd = rsqrtf(var + LN_EPS);
        tmp[t] = (snew - mean) * rstd * g_ff[t] + b_ff[t];
    }
    __syncthreads();
    float h = 0.f;
    if (t < DD) {
        h = b1[t];
        for (int d4 = 0; d4 < DD / 4; d4++) {
            float4 tv = *(const float4*)&tmp[d4 * 4];
            const float* wp = W1 + (size_t)(d4 * 4) * DD + t;
            h += tv.x * wp[0] + tv.y * wp[DD] + tv.z * wp[2 * DD] + tv.w * wp[3 * DD];
        }
        h = fmaxf(h, 0.f);
    }
    __syncthreads();
    if (t < DD) tmp[t] = h;
    __syncthreads();
    float o = 0.f;
    if (t < DD) {
        o = snew + b2[t];
        for (int d4 = 0; d4 < DD / 4; d4++) {
            float4 tv = *(const float4*)&tmp[d4 * 4];
            const float* wp = W2 + (size_t)(d4 * 4) * DD + t;
            o += tv.x * wp[0] + tv.y * wp[DD] + tv.z * wp[2 * DD] + tv.w * wp[3 * DD];
        }
        slots[(b * KK + kslot) * DD + t] = o;
    }
    // --- LN(o) + q for next iteration ---
    {
        float s_ = (t < DD) ? o : 0.f, sq_ = s_ * s_;
        #pragma unroll
        for (int o2 = 32; o2 > 0; o2 >>= 1) { s_ += __shfl_xor(s_, o2); sq_ += __shfl_xor(sq_, o2); }
        if (t < DD && (t & 63) == 0) { red[(t >> 6) * 2] = s_; red[(t >> 6) * 2 + 1] = sq_; }
    }
    __syncthreads();
    if (t < DD) {
        float mean = (red[0] + red[2]) * (1.0f / DD);
        float var  = (red[1] + red[3]) * (1.0f / DD) - mean * mean;
        float rstd = rsqrtf(var + LN_EPS);
        tmp[t] = (o - mean) * rstd * g_sl[t] + b_sl[t];
    }
    __syncthreads();
    if (t < DD) {
        float qv = bq[t];
        for (int d4 = 0; d4 < DD / 4; d4++) {
            float4 tv = *(const float4*)&tmp[d4 * 4];
            const float* wp = Wq + (size_t)(d4 * 4) * DD + t;
            qv += tv.x * wp[0] + tv.y * wp[DD] + tv.z * wp[2 * DD] + tv.w * wp[3 * DD];
        }
        q[(b * KK + kslot) * DD + t] = qv;
        if (last) {
            out_nf[(b * KK + kslot) * DD + t] = o;
            if (t < KK) out_adj[(b * KK + kslot) * KK + t] = 1.0f;
        }
    }
}

// ------------------------------------------------------------------
extern "C" void kernel_launch(void* const* d_in, const int* in_sizes, int n_in,
                              void* d_out, int out_size, void* d_ws, size_t ws_size,
                              hipStream_t stream) {
    (void)in_sizes; (void)n_in; (void)out_size; (void)ws_size;
    const float* x        = (const float*)d_in[0];
    const float* noise    = (const float*)d_in[1];
    const float* mu       = (const float*)d_in[2];
    const float* logsigma = (const float*)d_in[3];
    const float* Wq  = (const float*)d_in[4];
    const float* bq  = (const float*)d_in[5];
    const float* Wk  = (const float*)d_in[6];
    const float* bk  = (const float*)d_in[7];
    const float* Wv  = (const float*)d_in[8];
    const float* bv  = (const float*)d_in[9];
    const float* Wih = (const float*)d_in[10];
    const float* Whh = (const float*)d_in[11];
    const float* bih = (const float*)d_in[12];
    const float* bhh = (const float*)d_in[13];
    const float* W1  = (const float*)d_in[14];
    const float* b1  = (const float*)d_in[15];
    const float* W2  = (const float*)d_in[16];
    const float* b2  = (const float*)d_in[17];
    const float* g_in = (const float*)d_in[18];
    const float* b_in = (const float*)d_in[19];
    const float* g_sl = (const float*)d_in[20];
    const float* b_sl = (const float*)d_in[21];
    const float* g_ff = (const float*)d_in[22];
    const float* b_ff = (const float*)d_in[23];

    float* w = (float*)d_ws;
    ushort* kR   = (ushort*)(w + OFF_KR);
    ushort* vT   = (ushort*)(w + OFF_VT);
    ushort* WkvF = (ushort*)(w + OFF_WKVF);
    float* qbuf  = w + OFF_Q;
    float* slots = w + OFF_SLOTS;
    float* upart = w + OFF_UPART;
    float* dpart = w + OFF_DPART;
    float* svp   = w + OFF_SVP;
    float* sumv  = w + OFF_SUMV;
    float* WihT  = w + OFF_WIHT;
    float* WhhT  = w + OFF_WHHT;

    float* out_nf  = (float*)d_out;                       // [B,K,D]
    float* out_adj = out_nf + BB * KK * DD;               // [B,K,K]
    float* out_s   = out_adj + BB * KK * KK;              // [B,N,K]

    k_prep<<<320, 256, 0, stream>>>(Wih, Whh, Wk, Wv, WihT, WhhT, WkvF);
    k_ln_kv<<<BB * LNCH, 256, 0, stream>>>(x, WkvF, bk, bv, g_in, b_in,
                                           kR, vT, svp);
    k_sumv<<<BB, 128, 0, stream>>>(svp, sumv);
    k_init<<<BB * KK, 128, 0, stream>>>(noise, mu, logsigma, Wq, bq, g_sl, b_sl,
                                        slots, qbuf);

    for (int it = 0; it < N_ITERS; it++) {
        int last = (it == N_ITERS - 1) ? 1 : 0;
        k_attn<<<BB * NCH, 256, 0, stream>>>(kR, vT, qbuf, upart, dpart, out_s, last);
        k_slot<<<BB * KK, 384, 0, stream>>>(upart, dpart, sumv, WihT, WhhT,
                                            bih, bhh, W1, b1, W2, b2, Wq, bq,
                                            g_ff, b_ff, g_sl, b_sl,
                                            slots, qbuf, out_nf, out_adj, last);
    }
}